// Round 3
// baseline (624.560 us; speedup 1.0000x reference)
//
#include <hip/hip_runtime.h>

#define NN 10000
#define EE 640000
#define NT (EE / 16)

typedef __attribute__((ext_vector_type(8))) short bf16x8;
typedef __attribute__((ext_vector_type(4))) float f32x4;

// RTNE (prepass only)
__device__ __forceinline__ short f2bf(float f) {
  union { float f; unsigned u; } v; v.f = f;
  unsigned u = v.u + 0x7fffu + ((v.u >> 16) & 1u);
  return (short)(u >> 16);
}
// fast biased-round (hot loops): <=1 ulp
__device__ __forceinline__ unsigned f2bf_fast(float f) {
  union { float f; unsigned u; } v; v.f = f;
  return (v.u + 0x8000u) >> 16;
}
__device__ __forceinline__ float bf_lo(unsigned u) {
  union { unsigned x; float f; } p; p.x = u << 16; return p.f;
}
__device__ __forceinline__ float bf_hi(unsigned u) {
  union { unsigned x; float f; } p; p.x = u & 0xffff0000u; return p.f;
}
__device__ __forceinline__ float silu_f(float x) {
  return x / (1.0f + __expf(-x));
}
__device__ __forceinline__ f32x4 mfma16(bf16x8 a, bf16x8 b, f32x4 c) {
  return __builtin_amdgcn_mfma_f32_16x16x32_bf16(a, b, c, 0, 0, 0);
}

// ---------------------------------------------------------------------------
// Prepass: h -> bf16; weights -> bf16 transposed [n][k]
// ---------------------------------------------------------------------------
__global__ void k_cvt_h(const float* __restrict__ h, unsigned* __restrict__ h_bf) {
  const int i = blockIdx.x * 256 + threadIdx.x;   // over NN*64
  if (i < NN * 64) {
    const float2 v = ((const float2*)h)[i];
    h_bf[i] = (unsigned)(unsigned short)f2bf(v.x) |
              ((unsigned)(unsigned short)f2bf(v.y) << 16);
  }
}

__global__ void k_cvt_w(const float* __restrict__ We1, const float* __restrict__ We2,
                        const float* __restrict__ Wc1, const float* __restrict__ Wn1,
                        const float* __restrict__ Wn2,
                        unsigned short* __restrict__ We1t, unsigned short* __restrict__ We2t,
                        unsigned short* __restrict__ Wc1t, unsigned short* __restrict__ Wn1t,
                        unsigned short* __restrict__ Wn2t) {
  const int n = blockIdx.x;          // 128 blocks
  const int k = threadIdx.x;         // 256 threads
  We1t[n * 256 + k] = (unsigned short)f2bf(We1[k * 128 + n]);
  Wn1t[n * 256 + k] = (unsigned short)f2bf(Wn1[k * 128 + n]);
  if (k < 128) {
    We2t[n * 128 + k] = (unsigned short)f2bf(We2[k * 128 + n]);
    Wc1t[n * 128 + k] = (unsigned short)f2bf(Wc1[k * 128 + n]);
    Wn2t[n * 128 + k] = (unsigned short)f2bf(Wn2[k * 128 + n]);
  }
}

// ---------------------------------------------------------------------------
// CSR build
// ---------------------------------------------------------------------------
__global__ void k_hist(const int* __restrict__ ei, int* __restrict__ offs) {
  const int e = blockIdx.x * 256 + threadIdx.x;
  if (e < EE) atomicAdd(&offs[ei[e] + 1], 1);
}

__global__ void k_scan(int* __restrict__ offs) {
  __shared__ int buf[1024];
  __shared__ int base_s;
  if (threadIdx.x == 0) base_s = 0;
  __syncthreads();
  for (int c = 0; c < NN + 1; c += 1024) {
    const int i = c + (int)threadIdx.x;
    int v = (i <= NN) ? offs[i] : 0;
    buf[threadIdx.x] = v;
    __syncthreads();
    for (int d = 1; d < 1024; d <<= 1) {
      int t = (threadIdx.x >= (unsigned)d) ? buf[threadIdx.x - d] : 0;
      __syncthreads();
      buf[threadIdx.x] += t;
      __syncthreads();
    }
    const int out = buf[threadIdx.x] + base_s;
    if (i <= NN) offs[i] = out;
    __syncthreads();
    if (threadIdx.x == 1023) base_s = out;
    __syncthreads();
  }
}

__global__ void k_scatter(const int* __restrict__ ei, const int* __restrict__ offs,
                          int* __restrict__ cur, int* __restrict__ csr) {
  const int e = blockIdx.x * 256 + threadIdx.x;
  if (e < EE) {
    const int r = ei[e];
    const int pos = offs[r] + atomicAdd(&cur[r], 1);
    csr[pos] = e;
  }
}

// ---------------------------------------------------------------------------
// Edge kernel: CSR=true processes edges in csr order, streams ef (bf16, CSR
// order). CSR=false: atomic fallback into h_agg. Register-prefetch pipeline.
// ---------------------------------------------------------------------------
template <bool CSR>
__global__ __launch_bounds__(256, 2)
void egcl_edge2(const unsigned short* __restrict__ h_bf, const float* __restrict__ y,
                const int* __restrict__ ei, const int* __restrict__ csr,
                const unsigned short* __restrict__ We1t, const float* __restrict__ We1_last,
                const float* __restrict__ be1,
                const unsigned short* __restrict__ We2t, const float* __restrict__ be2,
                const unsigned short* __restrict__ Wc1t, const float* __restrict__ bc1,
                const float* __restrict__ Wc2,
                float* __restrict__ h_agg, float* __restrict__ agg4,
                unsigned short* __restrict__ ef)
{
  const int tid  = threadIdx.x;
  const int wave = tid >> 6;
  const int lane = tid & 63;
  const int l16  = lane & 15;
  const int quad = lane >> 4;
  const int n0   = wave * 32;

  __shared__ short A_lds[16 * 264];
  __shared__ short m1_lds[16 * 136];
  __shared__ short m2_lds[16 * 136];
  __shared__ float diff_lds[48];
  __shared__ float rad_lds[16];
  __shared__ int   row_lds[16];
  __shared__ float spart[4][16];

  // weight B-fragments from transposed bf16 (single dwordx4 each)
  bf16x8 wWe1[8][2], wWe2[4][2], wWc1[4][2];
  float w1last[2], b1v[2], b2v[2], bc1v[2], wc2v[2];
  #pragma unroll
  for (int t = 0; t < 2; ++t) {
    const int n = n0 + t * 16 + l16;
    #pragma unroll
    for (int kc = 0; kc < 8; ++kc)
      wWe1[kc][t] = *(const bf16x8*)(We1t + n * 256 + kc * 32 + quad * 8);
    #pragma unroll
    for (int kc = 0; kc < 4; ++kc) {
      wWe2[kc][t] = *(const bf16x8*)(We2t + n * 128 + kc * 32 + quad * 8);
      wWc1[kc][t] = *(const bf16x8*)(Wc1t + n * 128 + kc * 32 + quad * 8);
    }
    w1last[t] = We1_last[n];
    b1v[t] = be1[n]; b2v[t] = be2[n]; bc1v[t] = bc1[n]; wc2v[t] = Wc2[n];
  }

  const int e_sub = tid >> 4;
  const int s16   = tid & 15;

  // prologue prefetch
  int pr, pc;
  bf16x8 pva, pvb;
  float py0 = 0, py1 = 0, py2 = 0, pq0 = 0, pq1 = 0, pq2 = 0;
  {
    const int ge = blockIdx.x * 16 + e_sub;
    const int e = CSR ? csr[ge] : ge;
    pr = ei[e]; pc = ei[EE + e];
    pva = *(const bf16x8*)(h_bf + (size_t)pr * 128 + s16 * 8);
    pvb = *(const bf16x8*)(h_bf + (size_t)pc * 128 + s16 * 8);
    if (s16 == 0) {
      py0 = y[pr * 3]; py1 = y[pr * 3 + 1]; py2 = y[pr * 3 + 2];
      pq0 = y[pc * 3]; pq1 = y[pc * 3 + 1]; pq2 = y[pc * 3 + 2];
    }
  }

  for (int tile = blockIdx.x; tile < NT; tile += gridDim.x) {
    // ---- stage current (regs -> LDS) ----
    *(bf16x8*)(&A_lds[e_sub * 264 + s16 * 8])       = pva;
    *(bf16x8*)(&A_lds[e_sub * 264 + 128 + s16 * 8]) = pvb;
    if (s16 == 0) {
      row_lds[e_sub] = pr;
      const float dx = py0 - pq0, dy = py1 - pq1, dz = py2 - pq2;
      diff_lds[e_sub * 3 + 0] = dx;
      diff_lds[e_sub * 3 + 1] = dy;
      diff_lds[e_sub * 3 + 2] = dz;
      rad_lds[e_sub] = dx * dx + dy * dy + dz * dz;
    }
    // ---- issue prefetch for next tile ----
    const int ntile = tile + gridDim.x;
    if (ntile < NT) {
      const int ge = ntile * 16 + e_sub;
      const int e = CSR ? csr[ge] : ge;
      pr = ei[e]; pc = ei[EE + e];
      pva = *(const bf16x8*)(h_bf + (size_t)pr * 128 + s16 * 8);
      pvb = *(const bf16x8*)(h_bf + (size_t)pc * 128 + s16 * 8);
      if (s16 == 0) {
        py0 = y[pr * 3]; py1 = y[pr * 3 + 1]; py2 = y[pr * 3 + 2];
        pq0 = y[pc * 3]; pq1 = y[pc * 3 + 1]; pq2 = y[pc * 3 + 2];
      }
    }
    __syncthreads();

    // ---- layer 1: K=256 ----
    {
      f32x4 a00 = {0,0,0,0}, a01 = {0,0,0,0}, a10 = {0,0,0,0}, a11 = {0,0,0,0};
      #pragma unroll
      for (int kc = 0; kc < 8; kc += 2) {
        bf16x8 aA = *(const bf16x8*)(&A_lds[l16 * 264 + kc * 32 + quad * 8]);
        bf16x8 aB = *(const bf16x8*)(&A_lds[l16 * 264 + (kc + 1) * 32 + quad * 8]);
        a00 = mfma16(aA, wWe1[kc][0], a00);
        a10 = mfma16(aA, wWe1[kc][1], a10);
        a01 = mfma16(aB, wWe1[kc + 1][0], a01);
        a11 = mfma16(aB, wWe1[kc + 1][1], a11);
      }
      #pragma unroll
      for (int r = 0; r < 4; ++r) {
        const int m = quad * 4 + r;
        const float rad = rad_lds[m];
        float v0 = a00[r] + a01[r] + rad * w1last[0] + b1v[0];
        float v1 = a10[r] + a11[r] + rad * w1last[1] + b1v[1];
        m1_lds[m * 136 + n0 + l16]      = (short)f2bf_fast(silu_f(v0));
        m1_lds[m * 136 + n0 + 16 + l16] = (short)f2bf_fast(silu_f(v1));
      }
    }
    __syncthreads();

    // ---- layer 2: K=128 -> edge_feat ----
    float ef0[4], ef1[4];
    {
      f32x4 a00 = {0,0,0,0}, a01 = {0,0,0,0}, a10 = {0,0,0,0}, a11 = {0,0,0,0};
      #pragma unroll
      for (int kc = 0; kc < 4; kc += 2) {
        bf16x8 aA = *(const bf16x8*)(&m1_lds[l16 * 136 + kc * 32 + quad * 8]);
        bf16x8 aB = *(const bf16x8*)(&m1_lds[l16 * 136 + (kc + 1) * 32 + quad * 8]);
        a00 = mfma16(aA, wWe2[kc][0], a00);
        a10 = mfma16(aA, wWe2[kc][1], a10);
        a01 = mfma16(aB, wWe2[kc + 1][0], a01);
        a11 = mfma16(aB, wWe2[kc + 1][1], a11);
      }
      #pragma unroll
      for (int r = 0; r < 4; ++r) {
        const int m = quad * 4 + r;
        float v0 = silu_f(a00[r] + a01[r] + b2v[0]);
        float v1 = silu_f(a10[r] + a11[r] + b2v[1]);
        if (!CSR) { ef0[r] = v0; ef1[r] = v1; }
        m2_lds[m * 136 + n0 + l16]      = (short)f2bf_fast(v0);
        m2_lds[m * 136 + n0 + 16 + l16] = (short)f2bf_fast(v1);
      }
    }
    __syncthreads();

    // ---- ef stream (CSR order -> coalesced) or atomic fallback ----
    if (CSR) {
      bf16x8 v = *(const bf16x8*)(&m2_lds[e_sub * 136 + s16 * 8]);
      *(bf16x8*)(ef + (size_t)(tile * 16 + e_sub) * 128 + s16 * 8) = v;
    } else {
      #pragma unroll
      for (int r = 0; r < 4; ++r) {
        const int m = quad * 4 + r;
        const int node = row_lds[m];
        atomicAdd(&h_agg[(size_t)node * 128 + n0 + l16],      ef0[r]);
        atomicAdd(&h_agg[(size_t)node * 128 + n0 + 16 + l16], ef1[r]);
      }
    }
    // pre-read per-edge geometry for the tail (before spart barrier)
    float d0 = 0, d1 = 0, d2 = 0; int rnode = -1;
    if (tid < 16) {
      d0 = diff_lds[tid * 3 + 0];
      d1 = diff_lds[tid * 3 + 1];
      d2 = diff_lds[tid * 3 + 2];
      rnode = row_lds[tid];
    }

    // ---- layer 3: K=128 -> coord scalar ----
    {
      f32x4 a00 = {0,0,0,0}, a01 = {0,0,0,0}, a10 = {0,0,0,0}, a11 = {0,0,0,0};
      #pragma unroll
      for (int kc = 0; kc < 4; kc += 2) {
        bf16x8 aA = *(const bf16x8*)(&m2_lds[l16 * 136 + kc * 32 + quad * 8]);
        bf16x8 aB = *(const bf16x8*)(&m2_lds[l16 * 136 + (kc + 1) * 32 + quad * 8]);
        a00 = mfma16(aA, wWc1[kc][0], a00);
        a10 = mfma16(aA, wWc1[kc][1], a10);
        a01 = mfma16(aB, wWc1[kc + 1][0], a01);
        a11 = mfma16(aB, wWc1[kc + 1][1], a11);
      }
      float p[4];
      #pragma unroll
      for (int r = 0; r < 4; ++r) {
        float c0 = silu_f(a00[r] + a01[r] + bc1v[0]);
        float c1 = silu_f(a10[r] + a11[r] + bc1v[1]);
        p[r] = c0 * wc2v[0] + c1 * wc2v[1];
      }
      #pragma unroll
      for (int msk = 8; msk >= 1; msk >>= 1) {
        #pragma unroll
        for (int r = 0; r < 4; ++r) p[r] += __shfl_xor(p[r], msk, 64);
      }
      if (l16 == 0) {
        #pragma unroll
        for (int r = 0; r < 4; ++r) spart[wave][quad * 4 + r] = p[r];
      }
    }
    __syncthreads();

    // ---- tail: dedup same-node atomics within the 16-edge tile ----
    if (tid < 16) {
      const float s = spart[0][tid] + spart[1][tid] + spart[2][tid] + spart[3][tid];
      float a0 = 0, a1 = 0, a2 = 0, ac = 0;
      bool first = true;
      #pragma unroll
      for (int j = 0; j < 16; ++j) {
        const int   rj = __shfl(rnode, j, 64);
        const float sj = __shfl(s, j, 64);
        const float x0 = __shfl(d0, j, 64);
        const float x1 = __shfl(d1, j, 64);
        const float x2 = __shfl(d2, j, 64);
        if (rj == rnode) {
          if (j < tid) first = false;
          a0 += x0 * sj; a1 += x1 * sj; a2 += x2 * sj; ac += 1.0f;
        }
      }
      if (first) {
        atomicAdd(&agg4[rnode * 4 + 0], a0);
        atomicAdd(&agg4[rnode * 4 + 1], a1);
        atomicAdd(&agg4[rnode * 4 + 2], a2);
        if (!CSR) atomicAdd(&agg4[rnode * 4 + 3], ac);
      }
    }
  }
}

// ---------------------------------------------------------------------------
// Node kernel: CSR=true streams node-grouped ef rows; else reads h_agg f32.
// ---------------------------------------------------------------------------
template <bool CSR>
__global__ __launch_bounds__(256, 2)
void egcl_node2(const unsigned short* __restrict__ h_bf, const float* __restrict__ h,
                const float* __restrict__ y,
                const unsigned short* __restrict__ Wn1t, const float* __restrict__ bn1,
                const unsigned short* __restrict__ Wn2t, const float* __restrict__ bn2,
                const unsigned short* __restrict__ ef, const int* __restrict__ offs,
                const float* __restrict__ h_agg, const float* __restrict__ agg4,
                float* __restrict__ h_out, float* __restrict__ y_out)
{
  const int tid  = threadIdx.x;
  const int wave = tid >> 6;
  const int lane = tid & 63;
  const int l16  = lane & 15;
  const int quad = lane >> 4;
  const int n0   = wave * 32;

  __shared__ short A_lds[16 * 264];
  __shared__ short m1_lds[16 * 136];

  bf16x8 wWn1[8][2], wWn2[4][2];
  float bn1v[2], bn2v[2];
  #pragma unroll
  for (int t = 0; t < 2; ++t) {
    const int n = n0 + t * 16 + l16;
    #pragma unroll
    for (int kc = 0; kc < 8; ++kc)
      wWn1[kc][t] = *(const bf16x8*)(Wn1t + n * 256 + kc * 32 + quad * 8);
    #pragma unroll
    for (int kc = 0; kc < 4; ++kc)
      wWn2[kc][t] = *(const bf16x8*)(Wn2t + n * 128 + kc * 32 + quad * 8);
    bn1v[t] = bn1[n]; bn2v[t] = bn2[n];
  }

  const int node0 = blockIdx.x * 16;
  const int e_sub = tid >> 4;
  const int s16   = tid & 15;

  // stage h half (bf16 direct)
  {
    const int nd = node0 + e_sub;
    *(bf16x8*)(&A_lds[e_sub * 264 + s16 * 8]) =
        *(const bf16x8*)(h_bf + (size_t)nd * 128 + s16 * 8);
  }

  if (CSR) {
    // streaming gather: wave w sums nodes w*4..w*4+3; rows contiguous
    const unsigned* efu = (const unsigned*)ef;
    #pragma unroll
    for (int i = 0; i < 4; ++i) {
      const int lcl = wave * 4 + i;
      const int nd  = node0 + lcl;
      const int start = offs[nd], end = offs[nd + 1];
      float a0 = 0.f, a1 = 0.f;
      int e = start;
      for (; e + 8 <= end; e += 8) {
        unsigned u0 = efu[(size_t)(e + 0) * 64 + lane];
        unsigned u1 = efu[(size_t)(e + 1) * 64 + lane];
        unsigned u2 = efu[(size_t)(e + 2) * 64 + lane];
        unsigned u3 = efu[(size_t)(e + 3) * 64 + lane];
        unsigned u4 = efu[(size_t)(e + 4) * 64 + lane];
        unsigned u5 = efu[(size_t)(e + 5) * 64 + lane];
        unsigned u6 = efu[(size_t)(e + 6) * 64 + lane];
        unsigned u7 = efu[(size_t)(e + 7) * 64 + lane];
        a0 += bf_lo(u0) + bf_lo(u1) + bf_lo(u2) + bf_lo(u3)
            + bf_lo(u4) + bf_lo(u5) + bf_lo(u6) + bf_lo(u7);
        a1 += bf_hi(u0) + bf_hi(u1) + bf_hi(u2) + bf_hi(u3)
            + bf_hi(u4) + bf_hi(u5) + bf_hi(u6) + bf_hi(u7);
      }
      for (; e < end; ++e) {
        const unsigned u = efu[(size_t)e * 64 + lane];
        a0 += bf_lo(u); a1 += bf_hi(u);
      }
      const unsigned pk = (f2bf_fast(a0) & 0xffffu) | (f2bf_fast(a1) << 16);
      *(unsigned*)(&A_lds[lcl * 264 + 128 + lane * 2]) = pk;
      if (lane < 3) {
        const float inv = 1.0f / fmaxf((float)(end - start), 1.0f);
        y_out[nd * 3 + lane] = y[nd * 3 + lane] + agg4[nd * 4 + lane] * inv;
      }
    }
  } else {
    const int nd = node0 + e_sub;
    const float4* ha = (const float4*)(h_agg + (size_t)nd * 128);
    float4 b0 = ha[s16 * 2], b1 = ha[s16 * 2 + 1];
    bf16x8 vb;
    vb[0] = (short)f2bf_fast(b0.x); vb[1] = (short)f2bf_fast(b0.y);
    vb[2] = (short)f2bf_fast(b0.z); vb[3] = (short)f2bf_fast(b0.w);
    vb[4] = (short)f2bf_fast(b1.x); vb[5] = (short)f2bf_fast(b1.y);
    vb[6] = (short)f2bf_fast(b1.z); vb[7] = (short)f2bf_fast(b1.w);
    *(bf16x8*)(&A_lds[e_sub * 264 + 128 + s16 * 8]) = vb;
    if (tid < 16) {
      const int nd2 = node0 + tid;
      const float cnt = agg4[nd2 * 4 + 3];
      const float inv = 1.0f / fmaxf(cnt, 1.0f);
      y_out[nd2 * 3 + 0] = y[nd2 * 3 + 0] + agg4[nd2 * 4 + 0] * inv;
      y_out[nd2 * 3 + 1] = y[nd2 * 3 + 1] + agg4[nd2 * 4 + 1] * inv;
      y_out[nd2 * 3 + 2] = y[nd2 * 3 + 2] + agg4[nd2 * 4 + 2] * inv;
    }
  }
  __syncthreads();

  // layer 1: K=256
  {
    f32x4 a00 = {0,0,0,0}, a01 = {0,0,0,0}, a10 = {0,0,0,0}, a11 = {0,0,0,0};
    #pragma unroll
    for (int kc = 0; kc < 8; kc += 2) {
      bf16x8 aA = *(const bf16x8*)(&A_lds[l16 * 264 + kc * 32 + quad * 8]);
      bf16x8 aB = *(const bf16x8*)(&A_lds[l16 * 264 + (kc + 1) * 32 + quad * 8]);
      a00 = mfma16(aA, wWn1[kc][0], a00);
      a10 = mfma16(aA, wWn1[kc][1], a10);
      a01 = mfma16(aB, wWn1[kc + 1][0], a01);
      a11 = mfma16(aB, wWn1[kc + 1][1], a11);
    }
    #pragma unroll
    for (int r = 0; r < 4; ++r) {
      const int m = quad * 4 + r;
      float v0 = silu_f(a00[r] + a01[r] + bn1v[0]);
      float v1 = silu_f(a10[r] + a11[r] + bn1v[1]);
      m1_lds[m * 136 + n0 + l16]      = (short)f2bf_fast(v0);
      m1_lds[m * 136 + n0 + 16 + l16] = (short)f2bf_fast(v1);
    }
  }
  __syncthreads();

  // layer 2: K=128 + residual
  {
    f32x4 a00 = {0,0,0,0}, a01 = {0,0,0,0}, a10 = {0,0,0,0}, a11 = {0,0,0,0};
    #pragma unroll
    for (int kc = 0; kc < 4; kc += 2) {
      bf16x8 aA = *(const bf16x8*)(&m1_lds[l16 * 136 + kc * 32 + quad * 8]);
      bf16x8 aB = *(const bf16x8*)(&m1_lds[l16 * 136 + (kc + 1) * 32 + quad * 8]);
      a00 = mfma16(aA, wWn2[kc][0], a00);
      a10 = mfma16(aA, wWn2[kc][1], a10);
      a01 = mfma16(aB, wWn2[kc + 1][0], a01);
      a11 = mfma16(aB, wWn2[kc + 1][1], a11);
    }
    #pragma unroll
    for (int r = 0; r < 4; ++r) {
      const int m = quad * 4 + r;
      const int nd = node0 + m;
      const int na = n0 + l16;
      const int nb = n0 + 16 + l16;
      h_out[(size_t)nd * 128 + na] = h[(size_t)nd * 128 + na] + a00[r] + a01[r] + bn2v[0];
      h_out[(size_t)nd * 128 + nb] = h[(size_t)nd * 128 + nb] + a10[r] + a11[r] + bn2v[1];
    }
  }
}

extern "C" void kernel_launch(void* const* d_in, const int* in_sizes, int n_in,
                              void* d_out, int out_size, void* d_ws, size_t ws_size,
                              hipStream_t stream) {
  (void)in_sizes; (void)n_in; (void)out_size;
  const float* h   = (const float*)d_in[0];
  const float* y   = (const float*)d_in[1];
  const int*   ei  = (const int*)d_in[2];
  const float* We1 = (const float*)d_in[3];
  const float* be1 = (const float*)d_in[4];
  const float* We2 = (const float*)d_in[5];
  const float* be2 = (const float*)d_in[6];
  const float* Wc1 = (const float*)d_in[7];
  const float* bc1 = (const float*)d_in[8];
  const float* Wc2 = (const float*)d_in[9];
  const float* Wn1 = (const float*)d_in[10];
  const float* bn1 = (const float*)d_in[11];
  const float* Wn2 = (const float*)d_in[12];
  const float* bn2 = (const float*)d_in[13];
  const float* We1_last = We1 + 256 * 128;   // radial row

  float* h_out = (float*)d_out;
  float* y_out = h_out + (size_t)NN * 128;

  // workspace layout
  size_t off = 0;
  auto alloc = [&](size_t bytes) { size_t o = off; off = (off + bytes + 15) & ~(size_t)15; return o; };
  const size_t off_agg4 = alloc((size_t)NN * 4 * 4);
  const size_t off_offs = alloc((size_t)(NN + 1) * 4);
  const size_t off_cur  = alloc((size_t)NN * 4);
  const size_t off_hbf  = alloc((size_t)NN * 128 * 2);
  const size_t off_we1t = alloc((size_t)128 * 256 * 2);
  const size_t off_we2t = alloc((size_t)128 * 128 * 2);
  const size_t off_wc1t = alloc((size_t)128 * 128 * 2);
  const size_t off_wn1t = alloc((size_t)128 * 256 * 2);
  const size_t off_wn2t = alloc((size_t)128 * 128 * 2);
  const size_t base_need = off;              // ~6 MB (incl. agg4..cur zero region)
  const size_t off_csr  = alloc((size_t)EE * 4);
  const size_t off_ef   = alloc((size_t)EE * 128 * 2);
  const size_t csr_need = off;               // ~172.7 MB
  const size_t off_hagg = off_csr;           // fallback reuses csr slot region start
  const size_t fb_need  = off_csr + (size_t)NN * 128 * 4;

  char* w = (char*)d_ws;
  float* agg4 = (float*)(w + off_agg4);
  int* offs   = (int*)(w + off_offs);
  int* cur    = (int*)(w + off_cur);
  unsigned short* hbf  = (unsigned short*)(w + off_hbf);
  unsigned short* We1t = (unsigned short*)(w + off_we1t);
  unsigned short* We2t = (unsigned short*)(w + off_we2t);
  unsigned short* Wc1t = (unsigned short*)(w + off_wc1t);
  unsigned short* Wn1t = (unsigned short*)(w + off_wn1t);
  unsigned short* Wn2t = (unsigned short*)(w + off_wn2t);

  k_cvt_h<<<(NN * 64 + 255) / 256, 256, 0, stream>>>(h, (unsigned*)hbf);
  k_cvt_w<<<128, 256, 0, stream>>>(We1, We2, Wc1, Wn1, Wn2, We1t, We2t, Wc1t, Wn1t, Wn2t);

  if (ws_size >= csr_need) {
    int* csr = (int*)(w + off_csr);
    unsigned short* ef = (unsigned short*)(w + off_ef);
    hipMemsetAsync(w, 0, off_hbf, stream);   // agg4 + offs + cur
    k_hist<<<(EE + 255) / 256, 256, 0, stream>>>(ei, offs);
    k_scan<<<1, 1024, 0, stream>>>(offs);
    k_scatter<<<(EE + 255) / 256, 256, 0, stream>>>(ei, offs, cur, csr);
    egcl_edge2<true><<<2048, 256, 0, stream>>>(hbf, y, ei, csr, We1t, We1_last, be1,
                                               We2t, be2, Wc1t, bc1, Wc2,
                                               nullptr, agg4, ef);
    egcl_node2<true><<<NN / 16, 256, 0, stream>>>(hbf, h, y, Wn1t, bn1, Wn2t, bn2,
                                                  ef, offs, nullptr, agg4, h_out, y_out);
  } else {
    if (ws_size < fb_need) return;  // fail visibly
    float* h_agg = (float*)(w + off_hagg);
    hipMemsetAsync(w, 0, off_hbf, stream);                       // agg4 region
    hipMemsetAsync(h_agg, 0, (size_t)NN * 128 * 4, stream);      // h_agg
    egcl_edge2<false><<<2048, 256, 0, stream>>>(hbf, y, ei, nullptr, We1t, We1_last, be1,
                                                We2t, be2, Wc1t, bc1, Wc2,
                                                h_agg, agg4, nullptr);
    egcl_node2<false><<<NN / 16, 256, 0, stream>>>(hbf, h, y, Wn1t, bn1, Wn2t, bn2,
                                                   nullptr, nullptr, h_agg, agg4, h_out, y_out);
  }
  (void)base_need;
}

// Round 4
// 489.446 us; speedup vs baseline: 1.2761x; 1.2761x over previous
//
#include <hip/hip_runtime.h>

#define NN 10000
#define EE 640000
#define NT64 (EE / 64)   // 10000 tiles of 64 edges

typedef __attribute__((ext_vector_type(8))) short bf16x8;
typedef __attribute__((ext_vector_type(4))) float f32x4;

// RTNE (prepass)
__device__ __forceinline__ unsigned f2bf(float f) {
  union { float f; unsigned u; } v; v.f = f;
  return (v.u + 0x7fffu + ((v.u >> 16) & 1u)) >> 16;
}
// fast biased-round (hot loops): <=1 ulp
__device__ __forceinline__ unsigned f2bf_fast(float f) {
  union { float f; unsigned u; } v; v.f = f;
  return (v.u + 0x8000u) >> 16;
}
__device__ __forceinline__ float bf_lo(unsigned u) {
  union { unsigned x; float f; } p; p.x = u << 16; return p.f;
}
__device__ __forceinline__ float bf_hi(unsigned u) {
  union { unsigned x; float f; } p; p.x = u & 0xffff0000u; return p.f;
}
__device__ __forceinline__ float silu_f(float x) {
  return x / (1.0f + __expf(-x));
}
__device__ __forceinline__ f32x4 mfma16(bf16x8 a, bf16x8 b, f32x4 c) {
  return __builtin_amdgcn_mfma_f32_16x16x32_bf16(a, b, c, 0, 0, 0);
}

// ---------------------------------------------------------------------------
// Prepass: h -> bf16 (into d_out scratch); weights -> bf16 transposed [n][k]
// ---------------------------------------------------------------------------
__global__ void k_cvt_h(const float* __restrict__ h, unsigned* __restrict__ h_bf) {
  const int i = blockIdx.x * 256 + threadIdx.x;   // over NN*64
  if (i < NN * 64) {
    const float2 v = ((const float2*)h)[i];
    h_bf[i] = f2bf(v.x) | (f2bf(v.y) << 16);
  }
}

__global__ void k_cvt_w(const float* __restrict__ We1, const float* __restrict__ We2,
                        const float* __restrict__ Wc1, const float* __restrict__ Wn1,
                        const float* __restrict__ Wn2,
                        unsigned short* __restrict__ We1t, unsigned short* __restrict__ We2t,
                        unsigned short* __restrict__ Wc1t, unsigned short* __restrict__ Wn1t,
                        unsigned short* __restrict__ Wn2t) {
  const int n = blockIdx.x;          // 128 blocks
  const int k = threadIdx.x;         // 256 threads
  We1t[n * 256 + k] = (unsigned short)f2bf(We1[k * 128 + n]);
  Wn1t[n * 256 + k] = (unsigned short)f2bf(Wn1[k * 128 + n]);
  if (k < 128) {
    We2t[n * 128 + k] = (unsigned short)f2bf(We2[k * 128 + n]);
    Wc1t[n * 128 + k] = (unsigned short)f2bf(Wc1[k * 128 + n]);
    Wn2t[n * 128 + k] = (unsigned short)f2bf(Wn2[k * 128 + n]);
  }
}

// ---------------------------------------------------------------------------
// CSR build. k_scatter also emits packed (row,col) u16x2 and geometry
// (dx,dy,dz,rad) bf16x4 per edge in CSR order.
// ---------------------------------------------------------------------------
__global__ void k_hist(const int* __restrict__ ei, int* __restrict__ offs) {
  const int e = blockIdx.x * 256 + threadIdx.x;
  if (e < EE) atomicAdd(&offs[ei[e] + 1], 1);
}

__global__ void k_scan(int* __restrict__ offs) {
  __shared__ int buf[1024];
  __shared__ int base_s;
  if (threadIdx.x == 0) base_s = 0;
  __syncthreads();
  for (int c = 0; c < NN + 1; c += 1024) {
    const int i = c + (int)threadIdx.x;
    int v = (i <= NN) ? offs[i] : 0;
    buf[threadIdx.x] = v;
    __syncthreads();
    for (int d = 1; d < 1024; d <<= 1) {
      int t = (threadIdx.x >= (unsigned)d) ? buf[threadIdx.x - d] : 0;
      __syncthreads();
      buf[threadIdx.x] += t;
      __syncthreads();
    }
    const int out = buf[threadIdx.x] + base_s;
    if (i <= NN) offs[i] = out;
    __syncthreads();
    if (threadIdx.x == 1023) base_s = out;
    __syncthreads();
  }
}

__global__ void k_scatter(const int* __restrict__ ei, const float* __restrict__ y,
                          const int* __restrict__ offs, int* __restrict__ cur,
                          unsigned* __restrict__ rcbuf, uint2* __restrict__ diffpk) {
  const int e = blockIdx.x * 256 + threadIdx.x;
  if (e < EE) {
    const int r = ei[e];
    const int c = ei[EE + e];
    const int pos = offs[r] + atomicAdd(&cur[r], 1);
    rcbuf[pos] = (unsigned)r | ((unsigned)c << 16);
    const float dx = y[r * 3 + 0] - y[c * 3 + 0];
    const float dy = y[r * 3 + 1] - y[c * 3 + 1];
    const float dz = y[r * 3 + 2] - y[c * 3 + 2];
    const float rad = dx * dx + dy * dy + dz * dz;
    diffpk[pos] = make_uint2(f2bf(dx) | (f2bf(dy) << 16),
                             f2bf(dz) | (f2bf(rad) << 16));
  }
}

// ---------------------------------------------------------------------------
// Edge kernel: 64-edge tiles, 4 barriers per tile, zero atomics.
// Wave w owns cols [32w,32w+32). Writes ef (bf16, CSR order) and
// trans (bf16x3, in-place over diffpk).
// ---------------------------------------------------------------------------
__global__ __launch_bounds__(256, 2)
void egcl_edge3(const unsigned short* __restrict__ h_bf,
                const unsigned* __restrict__ rcbuf, uint2* __restrict__ diffpk,
                const unsigned short* __restrict__ We1t, const float* __restrict__ We1_last,
                const float* __restrict__ be1,
                const unsigned short* __restrict__ We2t, const float* __restrict__ be2,
                const unsigned short* __restrict__ Wc1t, const float* __restrict__ bc1,
                const float* __restrict__ Wc2,
                unsigned short* __restrict__ ef)
{
  const int tid  = threadIdx.x;
  const int wave = tid >> 6;
  const int lane = tid & 63;
  const int l16  = lane & 15;
  const int quad = lane >> 4;
  const int n0   = wave * 32;

  __shared__ short A_lds[64 * 264];    // 64 edges x K=256 (+8 pad)
  __shared__ short m1_lds[64 * 136];
  __shared__ short m2_lds[64 * 136];
  __shared__ float rad_lds[64];
  __shared__ float spart[4][64];

  // weight B-fragments in registers (bf16, transposed layout -> 1 dwordx4 each)
  bf16x8 wWe1[8][2], wWe2[4][2], wWc1[4][2];
  float w1last[2], b1v[2], b2v[2], bc1v[2], wc2v[2];
  #pragma unroll
  for (int t = 0; t < 2; ++t) {
    const int n = n0 + t * 16 + l16;
    #pragma unroll
    for (int kc = 0; kc < 8; ++kc)
      wWe1[kc][t] = *(const bf16x8*)(We1t + n * 256 + kc * 32 + quad * 8);
    #pragma unroll
    for (int kc = 0; kc < 4; ++kc) {
      wWe2[kc][t] = *(const bf16x8*)(We2t + n * 128 + kc * 32 + quad * 8);
      wWc1[kc][t] = *(const bf16x8*)(Wc1t + n * 128 + kc * 32 + quad * 8);
    }
    w1last[t] = We1_last[n];
    b1v[t] = be1[n]; b2v[t] = be2[n]; bc1v[t] = bc1[n]; wc2v[t] = Wc2[n];
  }

  const int e_sub = tid >> 4;   // 0..15
  const int s16   = tid & 15;   // 16B chunk within a 256B row

  for (int tile = blockIdx.x; tile < NT64; tile += gridDim.x) {
    // ---- stage A (gather h_bf rows; all coalesced/broadcast, no dep chains)
    #pragma unroll
    for (int i = 0; i < 4; ++i) {
      const int m = i * 16 + e_sub;
      const unsigned rcp = rcbuf[tile * 64 + m];
      const int r = rcp & 0xffffu;
      const int c = rcp >> 16;
      *(bf16x8*)(&A_lds[m * 264 + s16 * 8]) =
          *(const bf16x8*)(h_bf + (size_t)r * 128 + s16 * 8);
      *(bf16x8*)(&A_lds[m * 264 + 128 + s16 * 8]) =
          *(const bf16x8*)(h_bf + (size_t)c * 128 + s16 * 8);
    }
    float d0 = 0.f, d1 = 0.f, d2 = 0.f;
    if (tid < 64) {
      const uint2 dp = diffpk[tile * 64 + tid];
      d0 = bf_lo(dp.x); d1 = bf_hi(dp.x); d2 = bf_lo(dp.y);
      rad_lds[tid] = bf_hi(dp.y);
    }
    __syncthreads();

    // ---- layer 1: K=256, 4 M-subtiles ----
    #pragma unroll 2
    for (int si = 0; si < 4; ++si) {
      f32x4 a0 = {0,0,0,0}, a1 = {0,0,0,0};
      #pragma unroll
      for (int kc = 0; kc < 8; ++kc) {
        bf16x8 aA = *(const bf16x8*)(&A_lds[(si * 16 + l16) * 264 + kc * 32 + quad * 8]);
        a0 = mfma16(aA, wWe1[kc][0], a0);
        a1 = mfma16(aA, wWe1[kc][1], a1);
      }
      #pragma unroll
      for (int r = 0; r < 4; ++r) {
        const int m = si * 16 + quad * 4 + r;
        const float rad = rad_lds[m];
        float v0 = a0[r] + rad * w1last[0] + b1v[0];
        float v1 = a1[r] + rad * w1last[1] + b1v[1];
        m1_lds[m * 136 + n0 + l16]      = (short)f2bf_fast(silu_f(v0));
        m1_lds[m * 136 + n0 + 16 + l16] = (short)f2bf_fast(silu_f(v1));
      }
    }
    __syncthreads();

    // ---- layer 2: K=128 -> edge_feat ----
    #pragma unroll 2
    for (int si = 0; si < 4; ++si) {
      f32x4 a0 = {0,0,0,0}, a1 = {0,0,0,0};
      #pragma unroll
      for (int kc = 0; kc < 4; ++kc) {
        bf16x8 aA = *(const bf16x8*)(&m1_lds[(si * 16 + l16) * 136 + kc * 32 + quad * 8]);
        a0 = mfma16(aA, wWe2[kc][0], a0);
        a1 = mfma16(aA, wWe2[kc][1], a1);
      }
      #pragma unroll
      for (int r = 0; r < 4; ++r) {
        const int m = si * 16 + quad * 4 + r;
        m2_lds[m * 136 + n0 + l16]      = (short)f2bf_fast(silu_f(a0[r] + b2v[0]));
        m2_lds[m * 136 + n0 + 16 + l16] = (short)f2bf_fast(silu_f(a1[r] + b2v[1]));
      }
    }
    __syncthreads();

    // ---- ef stream (coalesced 256B rows, CSR order) ----
    #pragma unroll
    for (int i = 0; i < 4; ++i) {
      const int m = i * 16 + e_sub;
      bf16x8 v = *(const bf16x8*)(&m2_lds[m * 136 + s16 * 8]);
      *(bf16x8*)(ef + (size_t)(tile * 64 + m) * 128 + s16 * 8) = v;
    }

    // ---- layer 3: K=128 -> per-edge coord scalar ----
    #pragma unroll 2
    for (int si = 0; si < 4; ++si) {
      f32x4 a0 = {0,0,0,0}, a1 = {0,0,0,0};
      #pragma unroll
      for (int kc = 0; kc < 4; ++kc) {
        bf16x8 aA = *(const bf16x8*)(&m2_lds[(si * 16 + l16) * 136 + kc * 32 + quad * 8]);
        a0 = mfma16(aA, wWc1[kc][0], a0);
        a1 = mfma16(aA, wWc1[kc][1], a1);
      }
      float p[4];
      #pragma unroll
      for (int r = 0; r < 4; ++r) {
        float c0 = silu_f(a0[r] + bc1v[0]);
        float c1 = silu_f(a1[r] + bc1v[1]);
        p[r] = c0 * wc2v[0] + c1 * wc2v[1];
      }
      #pragma unroll
      for (int msk = 8; msk >= 1; msk >>= 1) {
        #pragma unroll
        for (int r = 0; r < 4; ++r) p[r] += __shfl_xor(p[r], msk, 64);
      }
      if (l16 == 0) {
        #pragma unroll
        for (int r = 0; r < 4; ++r) spart[wave][si * 16 + quad * 4 + r] = p[r];
      }
    }
    __syncthreads();

    // ---- tail: per-edge trans write (in-place over diffpk), no atomics ----
    if (tid < 64) {
      const float s = spart[0][tid] + spart[1][tid] + spart[2][tid] + spart[3][tid];
      diffpk[tile * 64 + tid] =
          make_uint2(f2bf_fast(d0 * s) | (f2bf_fast(d1 * s) << 16),
                     f2bf_fast(d2 * s));
    }
    // no barrier needed: next stage touches A_lds/rad_lds only (consumers done)
  }
}

// ---------------------------------------------------------------------------
// Node kernel: stream node-grouped ef + trans segments, then node MLP.
// ---------------------------------------------------------------------------
__global__ __launch_bounds__(256, 2)
void egcl_node3(const float* __restrict__ h, const float* __restrict__ y,
                const unsigned short* __restrict__ Wn1t, const float* __restrict__ bn1,
                const unsigned short* __restrict__ Wn2t, const float* __restrict__ bn2,
                const unsigned short* __restrict__ ef, const int* __restrict__ offs,
                const uint2* __restrict__ transpk,
                float* __restrict__ h_out, float* __restrict__ y_out)
{
  const int tid  = threadIdx.x;
  const int wave = tid >> 6;
  const int lane = tid & 63;
  const int l16  = lane & 15;
  const int quad = lane >> 4;
  const int n0   = wave * 32;

  __shared__ short A_lds[16 * 264];
  __shared__ short m1_lds[16 * 136];

  bf16x8 wWn1[8][2], wWn2[4][2];
  float bn1v[2], bn2v[2];
  #pragma unroll
  for (int t = 0; t < 2; ++t) {
    const int n = n0 + t * 16 + l16;
    #pragma unroll
    for (int kc = 0; kc < 8; ++kc)
      wWn1[kc][t] = *(const bf16x8*)(Wn1t + n * 256 + kc * 32 + quad * 8);
    #pragma unroll
    for (int kc = 0; kc < 4; ++kc)
      wWn2[kc][t] = *(const bf16x8*)(Wn2t + n * 128 + kc * 32 + quad * 8);
    bn1v[t] = bn1[n]; bn2v[t] = bn2[n];
  }

  const int node0 = blockIdx.x * 16;
  const int e_sub = tid >> 4;
  const int s16   = tid & 15;

  // stage h half (cvt from f32 — h_bf scratch is gone by now)
  {
    const int nd = node0 + e_sub;
    const float4* hr = (const float4*)(h + (size_t)nd * 128);
    float4 a0 = hr[s16 * 2], a1 = hr[s16 * 2 + 1];
    bf16x8 va;
    va[0] = (short)f2bf(a0.x); va[1] = (short)f2bf(a0.y);
    va[2] = (short)f2bf(a0.z); va[3] = (short)f2bf(a0.w);
    va[4] = (short)f2bf(a1.x); va[5] = (short)f2bf(a1.y);
    va[6] = (short)f2bf(a1.z); va[7] = (short)f2bf(a1.w);
    *(bf16x8*)(&A_lds[e_sub * 264 + s16 * 8]) = va;
  }

  // streaming CSR-segment sums: wave w handles nodes w*4..w*4+3
  const unsigned* efu = (const unsigned*)ef;
  #pragma unroll
  for (int i = 0; i < 4; ++i) {
    const int lcl = wave * 4 + i;
    const int nd  = node0 + lcl;
    const int start = offs[nd], end = offs[nd + 1];

    // ef sum: lane covers cols {2*lane, 2*lane+1}
    float a0 = 0.f, a1 = 0.f;
    int e = start;
    for (; e + 8 <= end; e += 8) {
      unsigned u0 = efu[(size_t)(e + 0) * 64 + lane];
      unsigned u1 = efu[(size_t)(e + 1) * 64 + lane];
      unsigned u2 = efu[(size_t)(e + 2) * 64 + lane];
      unsigned u3 = efu[(size_t)(e + 3) * 64 + lane];
      unsigned u4 = efu[(size_t)(e + 4) * 64 + lane];
      unsigned u5 = efu[(size_t)(e + 5) * 64 + lane];
      unsigned u6 = efu[(size_t)(e + 6) * 64 + lane];
      unsigned u7 = efu[(size_t)(e + 7) * 64 + lane];
      a0 += bf_lo(u0) + bf_lo(u1) + bf_lo(u2) + bf_lo(u3)
          + bf_lo(u4) + bf_lo(u5) + bf_lo(u6) + bf_lo(u7);
      a1 += bf_hi(u0) + bf_hi(u1) + bf_hi(u2) + bf_hi(u3)
          + bf_hi(u4) + bf_hi(u5) + bf_hi(u6) + bf_hi(u7);
    }
    for (; e < end; ++e) {
      const unsigned u = efu[(size_t)e * 64 + lane];
      a0 += bf_lo(u); a1 += bf_hi(u);
    }
    const unsigned pk = (f2bf_fast(a0) & 0xffffu) | (f2bf_fast(a1) << 16);
    *(unsigned*)(&A_lds[lcl * 264 + 128 + lane * 2]) = pk;

    // trans sum: lane strides edges
    float tx = 0.f, ty = 0.f, tz = 0.f;
    for (int e2 = start + lane; e2 < end; e2 += 64) {
      const uint2 up = transpk[e2];
      tx += bf_lo(up.x); ty += bf_hi(up.x); tz += bf_lo(up.y);
    }
    #pragma unroll
    for (int msk = 32; msk >= 1; msk >>= 1) {
      tx += __shfl_xor(tx, msk, 64);
      ty += __shfl_xor(ty, msk, 64);
      tz += __shfl_xor(tz, msk, 64);
    }
    if (lane < 3) {
      const float inv = 1.0f / fmaxf((float)(end - start), 1.0f);
      const float comp = (lane == 0) ? tx : (lane == 1) ? ty : tz;
      y_out[nd * 3 + lane] = y[nd * 3 + lane] + comp * inv;
    }
  }
  __syncthreads();

  // layer 1: K=256
  {
    f32x4 a00 = {0,0,0,0}, a01 = {0,0,0,0}, a10 = {0,0,0,0}, a11 = {0,0,0,0};
    #pragma unroll
    for (int kc = 0; kc < 8; kc += 2) {
      bf16x8 aA = *(const bf16x8*)(&A_lds[l16 * 264 + kc * 32 + quad * 8]);
      bf16x8 aB = *(const bf16x8*)(&A_lds[l16 * 264 + (kc + 1) * 32 + quad * 8]);
      a00 = mfma16(aA, wWn1[kc][0], a00);
      a10 = mfma16(aA, wWn1[kc][1], a10);
      a01 = mfma16(aB, wWn1[kc + 1][0], a01);
      a11 = mfma16(aB, wWn1[kc + 1][1], a11);
    }
    #pragma unroll
    for (int r = 0; r < 4; ++r) {
      const int m = quad * 4 + r;
      float v0 = silu_f(a00[r] + a01[r] + bn1v[0]);
      float v1 = silu_f(a10[r] + a11[r] + bn1v[1]);
      m1_lds[m * 136 + n0 + l16]      = (short)f2bf_fast(v0);
      m1_lds[m * 136 + n0 + 16 + l16] = (short)f2bf_fast(v1);
    }
  }
  __syncthreads();

  // layer 2: K=128 + residual
  {
    f32x4 a00 = {0,0,0,0}, a01 = {0,0,0,0}, a10 = {0,0,0,0}, a11 = {0,0,0,0};
    #pragma unroll
    for (int kc = 0; kc < 4; kc += 2) {
      bf16x8 aA = *(const bf16x8*)(&m1_lds[l16 * 136 + kc * 32 + quad * 8]);
      bf16x8 aB = *(const bf16x8*)(&m1_lds[l16 * 136 + (kc + 1) * 32 + quad * 8]);
      a00 = mfma16(aA, wWn2[kc][0], a00);
      a10 = mfma16(aA, wWn2[kc][1], a10);
      a01 = mfma16(aB, wWn2[kc + 1][0], a01);
      a11 = mfma16(aB, wWn2[kc + 1][1], a11);
    }
    #pragma unroll
    for (int r = 0; r < 4; ++r) {
      const int m = quad * 4 + r;
      const int nd = node0 + m;
      const int na = n0 + l16;
      const int nb = n0 + 16 + l16;
      h_out[(size_t)nd * 128 + na] = h[(size_t)nd * 128 + na] + a00[r] + a01[r] + bn2v[0];
      h_out[(size_t)nd * 128 + nb] = h[(size_t)nd * 128 + nb] + a10[r] + a11[r] + bn2v[1];
    }
  }
}

extern "C" void kernel_launch(void* const* d_in, const int* in_sizes, int n_in,
                              void* d_out, int out_size, void* d_ws, size_t ws_size,
                              hipStream_t stream) {
  (void)in_sizes; (void)n_in; (void)out_size;
  const float* h   = (const float*)d_in[0];
  const float* y   = (const float*)d_in[1];
  const int*   ei  = (const int*)d_in[2];
  const float* We1 = (const float*)d_in[3];
  const float* be1 = (const float*)d_in[4];
  const float* We2 = (const float*)d_in[5];
  const float* be2 = (const float*)d_in[6];
  const float* Wc1 = (const float*)d_in[7];
  const float* bc1 = (const float*)d_in[8];
  const float* Wc2 = (const float*)d_in[9];
  const float* Wn1 = (const float*)d_in[10];
  const float* bn1 = (const float*)d_in[11];
  const float* Wn2 = (const float*)d_in[12];
  const float* bn2 = (const float*)d_in[13];
  const float* We1_last = We1 + 256 * 128;   // radial row of We1

  float* h_out = (float*)d_out;
  float* y_out = h_out + (size_t)NN * 128;

  // --- d_out-resident scratch (read only by prepass + edge kernel, which
  //     complete before the node kernel overwrites h_out; stream-ordered) ---
  unsigned short* hbf = (unsigned short*)d_out;                 // 2.56 MB
  unsigned* rcbuf = (unsigned*)((char*)d_out + (size_t)NN * 128 * 2); // 2.56 MB
  // total 5.12 MB <= d_out size 5.24 MB

  // --- workspace layout (fits proven ws_size >= 169,429,392 B) ---
  size_t off = 0;
  auto alloc = [&](size_t bytes) { size_t o = off; off = (off + bytes + 15) & ~(size_t)15; return o; };
  const size_t off_offs = alloc((size_t)(NN + 1) * 4);
  const size_t off_cur  = alloc((size_t)NN * 4);
  const size_t zero_end = off;
  const size_t off_we1t = alloc((size_t)128 * 256 * 2);
  const size_t off_we2t = alloc((size_t)128 * 128 * 2);
  const size_t off_wc1t = alloc((size_t)128 * 128 * 2);
  const size_t off_wn1t = alloc((size_t)128 * 256 * 2);
  const size_t off_wn2t = alloc((size_t)128 * 128 * 2);
  const size_t off_dpk  = alloc((size_t)EE * 8);       // diffpk / transpk (shared)
  const size_t off_ef   = alloc((size_t)EE * 128 * 2); // 163.84 MB
  const size_t need = off;                              // ~169.27 MB
  if (ws_size < need) return;  // fail visibly (proven ws >= 169.43 MB)

  char* w = (char*)d_ws;
  int* offs   = (int*)(w + off_offs);
  int* cur    = (int*)(w + off_cur);
  unsigned short* We1t = (unsigned short*)(w + off_we1t);
  unsigned short* We2t = (unsigned short*)(w + off_we2t);
  unsigned short* Wc1t = (unsigned short*)(w + off_wc1t);
  unsigned short* Wn1t = (unsigned short*)(w + off_wn1t);
  unsigned short* Wn2t = (unsigned short*)(w + off_wn2t);
  uint2* diffpk = (uint2*)(w + off_dpk);
  unsigned short* ef = (unsigned short*)(w + off_ef);

  hipMemsetAsync(w, 0, zero_end, stream);   // offs + cur
  k_cvt_h<<<(NN * 64 + 255) / 256, 256, 0, stream>>>(h, (unsigned*)hbf);
  k_cvt_w<<<128, 256, 0, stream>>>(We1, We2, Wc1, Wn1, Wn2, We1t, We2t, Wc1t, Wn1t, Wn2t);
  k_hist<<<(EE + 255) / 256, 256, 0, stream>>>(ei, offs);
  k_scan<<<1, 1024, 0, stream>>>(offs);
  k_scatter<<<(EE + 255) / 256, 256, 0, stream>>>(ei, y, offs, cur, rcbuf, diffpk);
  egcl_edge3<<<2500, 256, 0, stream>>>(hbf, rcbuf, diffpk,
                                       We1t, We1_last, be1, We2t, be2,
                                       Wc1t, bc1, Wc2, ef);
  egcl_node3<<<NN / 16, 256, 0, stream>>>(h, y, Wn1t, bn1, Wn2t, bn2,
                                          ef, offs, diffpk, h_out, y_out);
}